// Round 1
// baseline (603.386 us; speedup 1.0000x reference)
//
#include <hip/hip_runtime.h>
#include <math.h>

// Problem constants
#define N_SP   2304      // H*W = 48*48
#define CC     256       // C
#define GG     8         // groups
#define CGD    16        // channels per group
#define INTERC 128       // C/2
#define BB     2         // batch

// ws layout (floats)
#define SZ_PROJ (2*2*8*2304*16)          // 1,179,648 per buffer
#define OFF_THETA 0
#define OFF_PHI   (SZ_PROJ)
#define OFF_GX    (2*SZ_PROJ)
#define OFF_ATTO  (3*SZ_PROJ)            // [sub][b][c=128][n]  (1,179,648)
#define OFF_WY    (4*SZ_PROJ)            // [sub][b][o=256][n]  (2,359,296)

struct ProjParams {
  const float* x[2];      // per sub
  const float* w[6];      // [sub*3 + proj], proj: 0=theta 1=phi 2=g
  const float* bias[6];
};

// ---------------------------------------------------------------------------
// K1: per-group 1x1 projections.  out[s][b][g][n][d] = sum_c w[g][d][c]*x[b][c][n] + bias[g][d]
// grid = 2(sub)*2(b)*8(g)*3(proj)*9(ntile) = 864 blocks, 256 threads
// ---------------------------------------------------------------------------
__global__ __launch_bounds__(256) void proj_kernel(ProjParams p, float* __restrict__ theta,
                                                   float* __restrict__ phi, float* __restrict__ gx)
{
  int bid = blockIdx.x;
  int nt   = bid % 9;  int r = bid / 9;
  int proj = r % 3;    r /= 3;
  int g    = r % 8;    r /= 8;
  int b    = r % 2;    int s = r / 2;
  int t = threadIdx.x;
  int n = nt * 256 + t;

  const float* w    = p.w[s*3 + proj];       // wave-uniform -> scalar loads
  const float* bias = p.bias[s*3 + proj];
  const float* xp   = p.x[s] + (size_t)b*CC*N_SP + n;
  float* outp = (proj == 0 ? theta : (proj == 1 ? phi : gx));
  outp += ((size_t)((s*2 + b)*8 + g) * N_SP + n) * CGD;

  float acc[16];
  #pragma unroll
  for (int d = 0; d < 16; ++d) acc[d] = bias[g*16 + d];

  const float* wg = w + g*16*256;            // [d][c] row-major
  for (int c0 = 0; c0 < 256; c0 += 16) {
    float xv[16];
    #pragma unroll
    for (int j = 0; j < 16; ++j) xv[j] = xp[(size_t)(c0 + j) * N_SP];
    #pragma unroll
    for (int d = 0; d < 16; ++d) {
      const float* wr = wg + d*256 + c0;     // uniform address
      #pragma unroll
      for (int j = 0; j < 16; ++j) acc[d] = fmaf(wr[j], xv[j], acc[d]);
    }
  }
  float4* o4 = (float4*)outp;
  #pragma unroll
  for (int q = 0; q < 4; ++q)
    o4[q] = make_float4(acc[4*q+0], acc[4*q+1], acc[4*q+2], acc[4*q+3]);
}

// ---------------------------------------------------------------------------
// K2: streaming attention with UNNORMALIZED softmax (|f| <~ 15, exp safe in fp32).
// One thread = one query row n.  Iterate all 2304 columns in 9 LDS tiles of 256.
// atto[s][b][g*16+d][n] = (sum_m exp(f[n,m]) * g[m][d]) / (sum_m exp(f[n,m]))
// grid = 2*2*8*9 = 288 blocks, 256 threads
// ---------------------------------------------------------------------------
__global__ __launch_bounds__(256) void attn_kernel(const float* __restrict__ theta,
                                                   const float* __restrict__ phi,
                                                   const float* __restrict__ gx,
                                                   float* __restrict__ atto)
{
  int bid = blockIdx.x;
  int nt = bid % 9;  int r = bid / 9;
  int g  = r % 8;    r /= 8;
  int b  = r % 2;    int s = r / 2;
  int t  = threadIdx.x;
  int n  = nt * 256 + t;
  size_t base = (size_t)((s*2 + b)*8 + g) * N_SP * CGD;

  const float4* th4 = (const float4*)(theta + base + (size_t)n * CGD);
  float4 t0 = th4[0], t1 = th4[1], t2 = th4[2], t3 = th4[3];

  __shared__ float4 sphi[256*4];   // 16 KB
  __shared__ float4 sgxs[256*4];   // 16 KB

  float acc[16];
  #pragma unroll
  for (int k = 0; k < 16; ++k) acc[k] = 0.f;
  float lsum = 0.f;

  for (int mt = 0; mt < 9; ++mt) {
    int m = mt * 256 + t;
    const float4* ph4 = (const float4*)(phi + base + (size_t)m * CGD);
    const float4* gx4 = (const float4*)(gx  + base + (size_t)m * CGD);
    __syncthreads();
    #pragma unroll
    for (int q = 0; q < 4; ++q) { sphi[t*4 + q] = ph4[q]; sgxs[t*4 + q] = gx4[q]; }
    __syncthreads();

    #pragma unroll 2
    for (int mm = 0; mm < 256; ++mm) {
      float4 p0 = sphi[mm*4+0], p1 = sphi[mm*4+1], p2 = sphi[mm*4+2], p3 = sphi[mm*4+3];
      // 4 parallel FMA chains for latency
      float s0 = fmaf(t0.x,p0.x, fmaf(t0.y,p0.y, fmaf(t0.z,p0.z, t0.w*p0.w)));
      float s1 = fmaf(t1.x,p1.x, fmaf(t1.y,p1.y, fmaf(t1.z,p1.z, t1.w*p1.w)));
      float s2 = fmaf(t2.x,p2.x, fmaf(t2.y,p2.y, fmaf(t2.z,p2.z, t2.w*p2.w)));
      float s3 = fmaf(t3.x,p3.x, fmaf(t3.y,p3.y, fmaf(t3.z,p3.z, t3.w*p3.w)));
      float sv = (s0 + s1) + (s2 + s3);
      float e = __expf(sv);
      lsum += e;
      float4 g0 = sgxs[mm*4+0], g1 = sgxs[mm*4+1], g2 = sgxs[mm*4+2], g3 = sgxs[mm*4+3];
      acc[ 0] = fmaf(e, g0.x, acc[ 0]); acc[ 1] = fmaf(e, g0.y, acc[ 1]);
      acc[ 2] = fmaf(e, g0.z, acc[ 2]); acc[ 3] = fmaf(e, g0.w, acc[ 3]);
      acc[ 4] = fmaf(e, g1.x, acc[ 4]); acc[ 5] = fmaf(e, g1.y, acc[ 5]);
      acc[ 6] = fmaf(e, g1.z, acc[ 6]); acc[ 7] = fmaf(e, g1.w, acc[ 7]);
      acc[ 8] = fmaf(e, g2.x, acc[ 8]); acc[ 9] = fmaf(e, g2.y, acc[ 9]);
      acc[10] = fmaf(e, g2.z, acc[10]); acc[11] = fmaf(e, g2.w, acc[11]);
      acc[12] = fmaf(e, g3.x, acc[12]); acc[13] = fmaf(e, g3.y, acc[13]);
      acc[14] = fmaf(e, g3.z, acc[14]); acc[15] = fmaf(e, g3.w, acc[15]);
    }
  }
  float inv = 1.f / lsum;
  float* op = atto + (size_t)(s*2 + b) * INTERC * N_SP + (size_t)(g*16) * N_SP + n;
  #pragma unroll
  for (int k = 0; k < 16; ++k) op[(size_t)k * N_SP] = acc[k] * inv;   // coalesced per d
}

// ---------------------------------------------------------------------------
// K3: W 1x1 conv: wy[s][b][o][n] = sum_{c<128} Ww[o][c]*atto[s][b][c][n] + Wb[o]
// grid = 2*2*16(otile)*9(ntile) = 576 blocks, 256 threads; 16 outputs/thread
// ---------------------------------------------------------------------------
__global__ __launch_bounds__(256) void wconv_kernel(const float* __restrict__ atto,
                                                    const float* __restrict__ Ww0, const float* __restrict__ Wb0,
                                                    const float* __restrict__ Ww1, const float* __restrict__ Wb1,
                                                    float* __restrict__ wy)
{
  int bid = blockIdx.x;
  int nt = bid % 9;   int r = bid / 9;
  int ot = r % 16;    r /= 16;
  int b  = r % 2;     int s = r / 2;
  int t  = threadIdx.x;
  int n  = nt * 256 + t;

  const float* Ww = s ? Ww1 : Ww0;   // (256,128) row-major [o][c]
  const float* Wb = s ? Wb1 : Wb0;
  const float* ain = atto + (size_t)(s*2 + b) * INTERC * N_SP + n;

  float acc[16];
  #pragma unroll
  for (int k = 0; k < 16; ++k) acc[k] = Wb[ot*16 + k];

  for (int c0 = 0; c0 < 128; c0 += 16) {
    float xv[16];
    #pragma unroll
    for (int j = 0; j < 16; ++j) xv[j] = ain[(size_t)(c0 + j) * N_SP];
    #pragma unroll
    for (int k = 0; k < 16; ++k) {
      const float* wr = Ww + (ot*16 + k)*128 + c0;   // uniform -> scalar loads
      #pragma unroll
      for (int j = 0; j < 16; ++j) acc[k] = fmaf(wr[j], xv[j], acc[k]);
    }
  }
  float* op = wy + (size_t)((s*2 + b)*CC + ot*16) * N_SP + n;
  #pragma unroll
  for (int k = 0; k < 16; ++k) op[(size_t)k * N_SP] = acc[k];
}

// ---------------------------------------------------------------------------
// K4: BatchNorm (training-mode batch stats over (b,n)) + residual + ReLU.
// grid = 2(sub)*256(o) = 512 blocks, 256 threads. Block reduces 4608 values.
// ---------------------------------------------------------------------------
__global__ __launch_bounds__(256) void bn_kernel(const float* __restrict__ wy,
                                                 const float* __restrict__ x0, const float* __restrict__ x1,
                                                 const float* __restrict__ g0, const float* __restrict__ b0,
                                                 const float* __restrict__ g1, const float* __restrict__ b1,
                                                 float* __restrict__ out)
{
  int o = blockIdx.x % 256;
  int s = blockIdx.x / 256;
  int t = threadIdx.x;
  const float* bng = s ? g1 : g0;
  const float* bnb = s ? b1 : b0;
  const float* xin = s ? x1 : x0;

  float sum = 0.f, ssq = 0.f;
  #pragma unroll
  for (int b2 = 0; b2 < 2; ++b2) {
    const float* wyp = wy + (size_t)((s*2 + b2)*CC + o) * N_SP;
    for (int n = t; n < N_SP; n += 256) { float v = wyp[n]; sum += v; ssq = fmaf(v, v, ssq); }
  }
  #pragma unroll
  for (int off = 32; off > 0; off >>= 1) {
    sum += __shfl_down(sum, off, 64);
    ssq += __shfl_down(ssq, off, 64);
  }
  __shared__ float red[8];
  __shared__ float sc[2];
  int wid = t >> 6, lane = t & 63;
  if (lane == 0) { red[wid] = sum; red[4 + wid] = ssq; }
  __syncthreads();
  if (t == 0) {
    float S = red[0] + red[1] + red[2] + red[3];
    float Q = red[4] + red[5] + red[6] + red[7];
    float mean = S * (1.f / 4608.f);
    float var  = Q * (1.f / 4608.f) - mean * mean;
    float rstd = rsqrtf(var + 1e-5f);
    float scale = bng[o] * rstd;
    sc[0] = scale;
    sc[1] = bnb[o] - mean * scale;
  }
  __syncthreads();
  float scale = sc[0], shift = sc[1];
  #pragma unroll
  for (int b2 = 0; b2 < 2; ++b2) {
    const float* wyp = wy + (size_t)((s*2 + b2)*CC + o) * N_SP;
    const float* xp  = xin + (size_t)(b2*CC + o) * N_SP;
    float* op = out + (size_t)s * BB*CC*N_SP + (size_t)(b2*CC + o) * N_SP;
    for (int n = t; n < N_SP; n += 256) {
      float v = fmaf(wyp[n], scale, shift) + xp[n];
      op[n] = fmaxf(v, 0.f);
    }
  }
}

// ---------------------------------------------------------------------------
extern "C" void kernel_launch(void* const* d_in, const int* in_sizes, int n_in,
                              void* d_out, int out_size, void* d_ws, size_t ws_size,
                              hipStream_t stream)
{
  const float* xc = (const float*)d_in[0];
  const float* xr = (const float*)d_in[1];
  // per-sub input bases: cls=2, reg=12; order: g_w,g_b,theta_w,theta_b,phi_w,phi_b,W_w,W_b,bn_g,bn_b
  ProjParams p;
  p.x[0] = xc; p.x[1] = xr;
  for (int s = 0; s < 2; ++s) {
    int bs = 2 + s * 10;
    p.w[s*3 + 0]    = (const float*)d_in[bs + 2];  // theta_w
    p.bias[s*3 + 0] = (const float*)d_in[bs + 3];
    p.w[s*3 + 1]    = (const float*)d_in[bs + 4];  // phi_w
    p.bias[s*3 + 1] = (const float*)d_in[bs + 5];
    p.w[s*3 + 2]    = (const float*)d_in[bs + 0];  // g_w
    p.bias[s*3 + 2] = (const float*)d_in[bs + 1];
  }

  float* ws    = (float*)d_ws;
  float* THETA = ws + OFF_THETA;
  float* PHI   = ws + OFF_PHI;
  float* GX    = ws + OFF_GX;
  float* ATTO  = ws + OFF_ATTO;
  float* WY    = ws + OFF_WY;

  proj_kernel<<<864, 256, 0, stream>>>(p, THETA, PHI, GX);
  attn_kernel<<<288, 256, 0, stream>>>(THETA, PHI, GX, ATTO);
  wconv_kernel<<<576, 256, 0, stream>>>(ATTO,
                                        (const float*)d_in[8],  (const float*)d_in[9],
                                        (const float*)d_in[18], (const float*)d_in[19], WY);
  bn_kernel<<<512, 256, 0, stream>>>(WY, xc, xr,
                                     (const float*)d_in[10], (const float*)d_in[11],
                                     (const float*)d_in[20], (const float*)d_in[21],
                                     (float*)d_out);
}

// Round 5
// 292.202 us; speedup vs baseline: 2.0650x; 2.0650x over previous
//
#include <hip/hip_runtime.h>
#include <math.h>

// Problem constants
#define N_SP   2304      // H*W = 48*48
#define CC     256       // C
#define GG     8         // groups
#define CGD    16        // channels per group
#define INTERC 128       // C/2
#define BB     2         // batch

typedef _Float16 v4h __attribute__((ext_vector_type(4)));
typedef short    v4s __attribute__((ext_vector_type(4)));
typedef float    v4f __attribute__((ext_vector_type(4)));

__device__ inline unsigned f32_to_bf16_rne(float f) {
  unsigned u = __builtin_bit_cast(unsigned, f);
  return (u + 0x7FFFu + ((u >> 16) & 1u)) >> 16;
}

// ws layout (bytes)
// THETA_h / PHI_h: [sbg=32][n=2304][16] f16          (2,359,296 B each)
// GT:              [sbg=32][d=16][m=2304] bf16 transposed (2,359,296 B)
// ATTO:            [sb=4][c=128][n=2304] f32          (4,718,592 B)
// WY:              [sb=4][o=256][n=2304] f32          (9,437,184 B)
#define OFF_TH   0
#define OFF_PH   2359296
#define OFF_GT   4718592
#define OFF_ATTO 7077888
#define OFF_WY   11796480

struct ProjParams {
  const float* x[2];      // per sub
  const float* w[6];      // [sub*3 + proj], proj: 0=theta 1=phi 2=g
  const float* bias[6];
};

// ---------------------------------------------------------------------------
// K1: per-group 1x1 projections.
//   theta/phi: [sbg][n][16] f16 contiguous;  g: transposed [sbg][d][m] bf16
// grid = 2*2*8*3*9 = 864 blocks, 256 threads
// ---------------------------------------------------------------------------
__global__ __launch_bounds__(256) void proj_kernel(ProjParams p, _Float16* __restrict__ theta,
                                                   _Float16* __restrict__ phi, unsigned short* __restrict__ gT)
{
  int bid = blockIdx.x;
  int nt   = bid % 9;  int r = bid / 9;
  int proj = r % 3;    r /= 3;
  int g    = r % 8;    r /= 8;
  int b    = r % 2;    int s = r / 2;
  int t = threadIdx.x;
  int n = nt * 256 + t;

  const float* w    = p.w[s*3 + proj];       // wave-uniform -> scalar loads
  const float* bias = p.bias[s*3 + proj];
  const float* xp   = p.x[s] + (size_t)b*CC*N_SP + n;
  int sbg = (s*2 + b)*8 + g;

  float acc[16];
  #pragma unroll
  for (int d = 0; d < 16; ++d) acc[d] = bias[g*16 + d];

  const float* wg = w + g*16*256;            // [d][c] row-major
  for (int c0 = 0; c0 < 256; c0 += 16) {
    float xv[16];
    #pragma unroll
    for (int j = 0; j < 16; ++j) xv[j] = xp[(size_t)(c0 + j) * N_SP];
    #pragma unroll
    for (int d = 0; d < 16; ++d) {
      const float* wr = wg + d*256 + c0;     // uniform address
      #pragma unroll
      for (int j = 0; j < 16; ++j) acc[d] = fmaf(wr[j], xv[j], acc[d]);
    }
  }

  if (proj < 2) {
    _Float16* outp = (proj == 0 ? theta : phi) + ((size_t)sbg * N_SP + n) * CGD;
    alignas(16) _Float16 h[16];
    #pragma unroll
    for (int d = 0; d < 16; ++d) h[d] = (_Float16)acc[d];
    uint4* o4 = (uint4*)outp;
    o4[0] = *(const uint4*)&h[0];
    o4[1] = *(const uint4*)&h[8];
  } else {
    unsigned short* outp = gT + (size_t)sbg * CGD * N_SP + n;   // [d][m], m=n
    #pragma unroll
    for (int d = 0; d < 16; ++d) outp[(size_t)d * N_SP] = (unsigned short)f32_to_bf16_rne(acc[d]);
  }
}

// ---------------------------------------------------------------------------
// K2: MFMA flash attention (unnormalized softmax, constant shift -8).
// Per wave: 16 query rows. mfma1 (f16): S^T = phi_tile * theta^T.
//   S^T C-layout == A-layout of P for mfma2 -> no LDS roundtrip.
// P/g in BF16 (fp32 exponent range): e=exp(f-8) never overflows, ratios
// preserved to 0.2% which cancels in num/denom. No clamp needed.
// grid = 32 sbg * 36 ntiles = 1152 blocks, 256 threads (4 waves, 64 rows/blk)
// ---------------------------------------------------------------------------
__global__ __launch_bounds__(256) void attn_kernel(const _Float16* __restrict__ theta,
                                                   const _Float16* __restrict__ phi,
                                                   const unsigned short* __restrict__ gT,
                                                   float* __restrict__ atto)
{
  __shared__ short sphi[256 * 20];   // phi chunk [m_local][16], row stride 20 halves (40 B)
  __shared__ short sgt [16 * 260];   // gT chunk [d][m_local] bf16, row stride 260 (520 B)
  __shared__ float redl[4][16];

  int bid = blockIdx.x;
  int nt  = bid % 36;
  int sbg = bid / 36;
  int g   = sbg & 7;
  int sb  = sbg >> 3;                // s*2+b

  int tid  = threadIdx.x;
  int lane = tid & 63;
  int wv   = tid >> 6;
  int l15  = lane & 15;
  int quad = lane >> 4;

  size_t base16 = (size_t)sbg * N_SP * CGD;

  // B-frag theta for this wave's 16 rows, loaded once: B[k=quad*4+j][n=l15]
  int n_row = nt*64 + wv*16 + l15;
  v4h bTheta = __builtin_bit_cast(v4h,
      *(const uint2*)(theta + base16 + (size_t)n_row*16 + quad*4));

  v4f acc = {0.f, 0.f, 0.f, 0.f};
  float lsum = 0.f;

  for (int c0 = 0; c0 < N_SP; c0 += 256) {
    __syncthreads();
    // stage phi rows c0..c0+255 (32 B per thread)
    {
      const uint4* src = (const uint4*)(phi + base16 + (size_t)(c0 + tid)*16);
      uint4 v0 = src[0], v1 = src[1];
      uint2* dst = (uint2*)((char*)sphi + tid*40);
      dst[0] = make_uint2(v0.x, v0.y); dst[1] = make_uint2(v0.z, v0.w);
      dst[2] = make_uint2(v1.x, v1.y); dst[3] = make_uint2(v1.z, v1.w);
      // stage gT: 16 rows x 256 halves (bf16 bits, bitwise copy)
      int d = tid >> 4, seg = tid & 15;
      const uint4* gs = (const uint4*)(gT + base16 + (size_t)d*N_SP + c0 + seg*16);
      uint4 g0 = gs[0], g1 = gs[1];
      uint2* gd = (uint2*)((char*)sgt + d*520 + seg*32);
      gd[0] = make_uint2(g0.x, g0.y); gd[1] = make_uint2(g0.z, g0.w);
      gd[2] = make_uint2(g1.x, g1.y); gd[3] = make_uint2(g1.z, g1.w);
    }
    __syncthreads();

    #pragma unroll 4
    for (int sub = 0; sub < 16; ++sub) {
      int mb = sub * 16;
      // A-frag phi: A[m=l15][k=quad*4+j]
      v4h aPhi = __builtin_bit_cast(v4h,
          *(const uint2*)((const char*)sphi + (size_t)(mb + l15)*40 + quad*8));
      v4f S = __builtin_amdgcn_mfma_f32_16x16x16f16(aPhi, bTheta, (v4f){0.f,0.f,0.f,0.f}, 0, 0, 0);
      // lane holds S[n=l15][m = c0+mb+quad*4+r]
      float e0 = __expf(S[0] - 8.f);
      float e1 = __expf(S[1] - 8.f);
      float e2 = __expf(S[2] - 8.f);
      float e3 = __expf(S[3] - 8.f);
      lsum += (e0 + e1) + (e2 + e3);
      unsigned lo = f32_to_bf16_rne(e0) | (f32_to_bf16_rne(e1) << 16);
      unsigned hi = f32_to_bf16_rne(e2) | (f32_to_bf16_rne(e3) << 16);
      v4s P = __builtin_bit_cast(v4s, make_uint2(lo, hi));   // A[n=l15][k=quad*4+j]
      // B-frag g (bf16): B[k=quad*4+j][d=l15] from gT chunk
      v4s gf = __builtin_bit_cast(v4s,
          *(const uint2*)((const char*)sgt + (size_t)l15*520 + (size_t)(mb + quad*4)*2));
      acc = __builtin_amdgcn_mfma_f32_16x16x16bf16_1k(P, gf, acc, 0, 0, 0);
    }
  }

  // reduce lsum across quads (lanes sharing l15)
  lsum += __shfl_xor(lsum, 16, 64);
  lsum += __shfl_xor(lsum, 32, 64);
  if (lane < 16) redl[wv][lane] = lsum;
  __syncthreads();

  // acc C-layout: row n_local = quad*4+r, col d = l15
  float* op = atto + (size_t)sb * INTERC * N_SP + (size_t)(g*16 + l15) * N_SP + nt*64 + wv*16;
  #pragma unroll
  for (int r2 = 0; r2 < 4; ++r2) {
    float ls = redl[wv][quad*4 + r2];
    op[quad*4 + r2] = acc[r2] / ls;
  }
}

// ---------------------------------------------------------------------------
// K3: W 1x1 conv: wy[s][b][o][n] = sum_{c<128} Ww[o][c]*atto[s][b][c][n] + Wb[o]
// grid = 2*2*16(otile)*9(ntile) = 576 blocks, 256 threads; 16 outputs/thread
// ---------------------------------------------------------------------------
__global__ __launch_bounds__(256) void wconv_kernel(const float* __restrict__ atto,
                                                    const float* __restrict__ Ww0, const float* __restrict__ Wb0,
                                                    const float* __restrict__ Ww1, const float* __restrict__ Wb1,
                                                    float* __restrict__ wy)
{
  int bid = blockIdx.x;
  int nt = bid % 9;   int r = bid / 9;
  int ot = r % 16;    r /= 16;
  int b  = r % 2;     int s = r / 2;
  int t  = threadIdx.x;
  int n  = nt * 256 + t;

  const float* Ww = s ? Ww1 : Ww0;   // (256,128) row-major [o][c]
  const float* Wb = s ? Wb1 : Wb0;
  const float* ain = atto + (size_t)(s*2 + b) * INTERC * N_SP + n;

  float acc[16];
  #pragma unroll
  for (int k = 0; k < 16; ++k) acc[k] = Wb[ot*16 + k];

  for (int c0 = 0; c0 < 128; c0 += 16) {
    float xv[16];
    #pragma unroll
    for (int j = 0; j < 16; ++j) xv[j] = ain[(size_t)(c0 + j) * N_SP];
    #pragma unroll
    for (int k = 0; k < 16; ++k) {
      const float* wr = Ww + (ot*16 + k)*128 + c0;   // uniform -> scalar loads
      #pragma unroll
      for (int j = 0; j < 16; ++j) acc[k] = fmaf(wr[j], xv[j], acc[k]);
    }
  }
  float* op = wy + (size_t)((s*2 + b)*CC + ot*16) * N_SP + n;
  #pragma unroll
  for (int k = 0; k < 16; ++k) op[(size_t)k * N_SP] = acc[k];
}

// ---------------------------------------------------------------------------
// K4: BatchNorm (training-mode batch stats over (b,n)) + residual + ReLU.
// grid = 2(sub)*256(o) = 512 blocks, 256 threads. Block reduces 4608 values.
// ---------------------------------------------------------------------------
__global__ __launch_bounds__(256) void bn_kernel(const float* __restrict__ wy,
                                                 const float* __restrict__ x0, const float* __restrict__ x1,
                                                 const float* __restrict__ g0, const float* __restrict__ b0,
                                                 const float* __restrict__ g1, const float* __restrict__ b1,
                                                 float* __restrict__ out)
{
  int o = blockIdx.x % 256;
  int s = blockIdx.x / 256;
  int t = threadIdx.x;
  const float* bng = s ? g1 : g0;
  const float* bnb = s ? b1 : b0;
  const float* xin = s ? x1 : x0;

  float sum = 0.f, ssq = 0.f;
  #pragma unroll
  for (int b2 = 0; b2 < 2; ++b2) {
    const float* wyp = wy + (size_t)((s*2 + b2)*CC + o) * N_SP;
    for (int n = t; n < N_SP; n += 256) { float v = wyp[n]; sum += v; ssq = fmaf(v, v, ssq); }
  }
  #pragma unroll
  for (int off = 32; off > 0; off >>= 1) {
    sum += __shfl_down(sum, off, 64);
    ssq += __shfl_down(ssq, off, 64);
  }
  __shared__ float red[8];
  __shared__ float sc[2];
  int wid = t >> 6, lane = t & 63;
  if (lane == 0) { red[wid] = sum; red[4 + wid] = ssq; }
  __syncthreads();
  if (t == 0) {
    float S = red[0] + red[1] + red[2] + red[3];
    float Q = red[4] + red[5] + red[6] + red[7];
    float mean = S * (1.f / 4608.f);
    float var  = Q * (1.f / 4608.f) - mean * mean;
    float rstd = rsqrtf(var + 1e-5f);
    float scale = bng[o] * rstd;
    sc[0] = scale;
    sc[1] = bnb[o] - mean * scale;
  }
  __syncthreads();
  float scale = sc[0], shift = sc[1];
  #pragma unroll
  for (int b2 = 0; b2 < 2; ++b2) {
    const float* wyp = wy + (size_t)((s*2 + b2)*CC + o) * N_SP;
    const float* xp  = xin + (size_t)(b2*CC + o) * N_SP;
    float* op = out + (size_t)s * BB*CC*N_SP + (size_t)(b2*CC + o) * N_SP;
    for (int n = t; n < N_SP; n += 256) {
      float v = fmaf(wyp[n], scale, shift) + xp[n];
      op[n] = fmaxf(v, 0.f);
    }
  }
}

// ---------------------------------------------------------------------------
extern "C" void kernel_launch(void* const* d_in, const int* in_sizes, int n_in,
                              void* d_out, int out_size, void* d_ws, size_t ws_size,
                              hipStream_t stream)
{
  const float* xc = (const float*)d_in[0];
  const float* xr = (const float*)d_in[1];
  // per-sub input bases: cls=2, reg=12; order: g_w,g_b,theta_w,theta_b,phi_w,phi_b,W_w,W_b,bn_g,bn_b
  ProjParams p;
  p.x[0] = xc; p.x[1] = xr;
  for (int s = 0; s < 2; ++s) {
    int bs = 2 + s * 10;
    p.w[s*3 + 0]    = (const float*)d_in[bs + 2];  // theta_w
    p.bias[s*3 + 0] = (const float*)d_in[bs + 3];
    p.w[s*3 + 1]    = (const float*)d_in[bs + 4];  // phi_w
    p.bias[s*3 + 1] = (const float*)d_in[bs + 5];
    p.w[s*3 + 2]    = (const float*)d_in[bs + 0];  // g_w
    p.bias[s*3 + 2] = (const float*)d_in[bs + 1];
  }

  char* wsb = (char*)d_ws;
  _Float16*       THETA = (_Float16*)(wsb + OFF_TH);
  _Float16*       PHI   = (_Float16*)(wsb + OFF_PH);
  unsigned short* GT    = (unsigned short*)(wsb + OFF_GT);
  float*          ATTO  = (float*)(wsb + OFF_ATTO);
  float*          WY    = (float*)(wsb + OFF_WY);

  proj_kernel<<<864, 256, 0, stream>>>(p, THETA, PHI, GT);
  attn_kernel<<<1152, 256, 0, stream>>>(THETA, PHI, GT, ATTO);
  wconv_kernel<<<576, 256, 0, stream>>>(ATTO,
                                        (const float*)d_in[8],  (const float*)d_in[9],
                                        (const float*)d_in[18], (const float*)d_in[19], WY);
  bn_kernel<<<512, 256, 0, stream>>>(WY, xc, xr,
                                     (const float*)d_in[10], (const float*)d_in[11],
                                     (const float*)d_in[20], (const float*)d_in[21],
                                     (float*)d_out);
}

// Round 6
// 216.296 us; speedup vs baseline: 2.7896x; 1.3509x over previous
//
#include <hip/hip_runtime.h>
#include <math.h>

// Problem constants
#define N_SP   2304      // H*W = 48*48
#define CC     256       // C
#define GG     8         // groups
#define CGD    16        // channels per group
#define INTERC 128       // C/2
#define BB     2         // batch

typedef _Float16 v4h __attribute__((ext_vector_type(4)));
typedef short    v4s __attribute__((ext_vector_type(4)));
typedef float    v4f __attribute__((ext_vector_type(4)));

__device__ inline unsigned f32_to_bf16_rne(float f) {
  unsigned u = __builtin_bit_cast(unsigned, f);
  return (u + 0x7FFFu + ((u >> 16) & 1u)) >> 16;
}

// ws layout (bytes)
// XT:   [sb=4][n=2304][c=256] f16 (x transposed)      4,718,592
// WH:   [s*3+proj][128 rows][256] f16 packed            393,216
// WWB:  [s][256 o][128 c] bf16 packed                   131,072
// THETA/PHI: [sbg=32][n=2304][16] f16                 2,359,296 each
// GT:   [sbg=32][d=16][m=2304] bf16                   2,359,296
// AT:   [sb=4][n=2304][c=128] bf16 (attn out, n-major) 2,359,296
// WY:   [sb=4][o=256][n=2304] f32                     9,437,184
#define OFF_XT   0
#define OFF_WH   4718592
#define OFF_WWB  5111808
#define OFF_TH   5242880
#define OFF_PH   7602176
#define OFF_GT   9961472
#define OFF_AT   12320768
#define OFF_WY   14680064

struct PackP { const float* src[8]; };   // 0..5: proj weights (s*3+proj), 6..7: W_w per s
struct BiasP { const float* b[6]; };     // s*3+proj

// ---------------------------------------------------------------------------
// K0a: pack weights fp32 -> f16 (proj) / bf16 (W). 8 arrays x 32768 elems.
// grid = 1024 x 256
// ---------------------------------------------------------------------------
__global__ __launch_bounds__(256) void pack_kernel(PackP p, _Float16* __restrict__ wh,
                                                   unsigned short* __restrict__ wwb)
{
  int bid = blockIdx.x;
  int seg = bid >> 7;                              // 0..7
  int i = ((bid & 127) << 8) | threadIdx.x;        // 0..32767
  float v = p.src[seg][i];
  if (seg < 6) wh[seg * 32768 + i] = (_Float16)v;
  else         wwb[(seg - 6) * 32768 + i] = (unsigned short)f32_to_bf16_rne(v);
}

// ---------------------------------------------------------------------------
// K0b: transpose+convert x fp32 [c][n] -> XT f16 [n][c]. 64x64 LDS tiles.
// grid = 4(sb) * 36(nt) * 4(ct) = 576 x 256
// ---------------------------------------------------------------------------
__global__ __launch_bounds__(256) void transpose_kernel(const float* __restrict__ x0,
                                                        const float* __restrict__ x1,
                                                        _Float16* __restrict__ xt)
{
  __shared__ float ld[64][65];
  int bid = blockIdx.x;
  int ct = bid & 3;
  int nt = (bid >> 2) % 36;
  int sb = bid / 144;
  const float* src = ((sb >> 1) ? x1 : x0) + (size_t)(sb & 1) * CC * N_SP;
  int t = threadIdx.x;
  int col = t & 63, rq = t >> 6;
  #pragma unroll
  for (int i = 0; i < 16; ++i) {
    int row = i * 4 + rq;
    ld[row][col] = src[(size_t)(ct * 64 + row) * N_SP + nt * 64 + col];
  }
  __syncthreads();
  int nl = t >> 2, cs = (t & 3) * 16;
  float v[16];
  #pragma unroll
  for (int j = 0; j < 16; ++j) v[j] = ld[cs + j][nl];
  unsigned u[8];
  #pragma unroll
  for (int j = 0; j < 8; ++j)
    u[j] = __builtin_bit_cast(unsigned, __builtin_amdgcn_cvt_pkrtz(v[2*j], v[2*j+1]));
  _Float16* dst = xt + ((size_t)sb * N_SP + nt * 64 + nl) * 256 + ct * 64 + cs;
  uint4* d4 = (uint4*)dst;
  d4[0] = make_uint4(u[0], u[1], u[2], u[3]);
  d4[1] = make_uint4(u[4], u[5], u[6], u[7]);
}

// ---------------------------------------------------------------------------
// K1: proj via MFMA. Per (sb, proj): O[128 rows][2304 n] = WH[128][256] * X.
// A-frag from WH (row-major, contiguous k), B-frag from XT[n][c] (contiguous k).
// grid = 4(sb)*3(proj)*36(nt of 64) = 432 x 256; wave tile 32 rows x 64 n.
// ---------------------------------------------------------------------------
__global__ __launch_bounds__(256) void proj_mfma(BiasP bp, const _Float16* __restrict__ wh,
                                                 const _Float16* __restrict__ xt,
                                                 _Float16* __restrict__ theta, _Float16* __restrict__ phi,
                                                 unsigned short* __restrict__ gT)
{
  int bid = blockIdx.x;
  int nt   = bid % 36;
  int proj = (bid / 36) % 3;
  int sb   = bid / 108;
  int s    = sb >> 1;
  int tid = threadIdx.x, lane = tid & 63, wv = tid >> 6;
  int l15 = lane & 15, quad = lane >> 4;

  const _Float16* A = wh + (size_t)(s * 3 + proj) * 32768;
  const _Float16* B = xt + (size_t)sb * N_SP * 256;

  v4f acc[2][4];
  #pragma unroll
  for (int rt = 0; rt < 2; ++rt)
    #pragma unroll
    for (int c = 0; c < 4; ++c) acc[rt][c] = (v4f){0.f, 0.f, 0.f, 0.f};

  #pragma unroll 2
  for (int k0 = 0; k0 < 256; k0 += 16) {
    v4h a[2], b[4];
    #pragma unroll
    for (int rt = 0; rt < 2; ++rt) {
      int row = wv * 32 + rt * 16 + l15;
      a[rt] = __builtin_bit_cast(v4h, *(const uint2*)(A + (size_t)row * 256 + k0 + quad * 4));
    }
    #pragma unroll
    for (int c = 0; c < 4; ++c) {
      int n = nt * 64 + c * 16 + l15;
      b[c] = __builtin_bit_cast(v4h, *(const uint2*)(B + (size_t)n * 256 + k0 + quad * 4));
    }
    #pragma unroll
    for (int rt = 0; rt < 2; ++rt)
      #pragma unroll
      for (int c = 0; c < 4; ++c)
        acc[rt][c] = __builtin_amdgcn_mfma_f32_16x16x16f16(a[rt], b[c], acc[rt][c], 0, 0, 0);
  }

  const float* bias = bp.b[s * 3 + proj];
  #pragma unroll
  for (int rt = 0; rt < 2; ++rt) {
    int g   = wv * 2 + rt;            // row tile == group (rows = g*16+d)
    int sbg = sb * 8 + g;
    float bv[4];
    #pragma unroll
    for (int r = 0; r < 4; ++r) bv[r] = bias[g * 16 + quad * 4 + r];
    if (proj < 2) {
      _Float16* outp = (proj == 0 ? theta : phi);
      #pragma unroll
      for (int c = 0; c < 4; ++c) {
        int n = nt * 64 + c * 16 + l15;
        unsigned u0 = __builtin_bit_cast(unsigned,
            __builtin_amdgcn_cvt_pkrtz(acc[rt][c][0] + bv[0], acc[rt][c][1] + bv[1]));
        unsigned u1 = __builtin_bit_cast(unsigned,
            __builtin_amdgcn_cvt_pkrtz(acc[rt][c][2] + bv[2], acc[rt][c][3] + bv[3]));
        *(uint2*)(outp + ((size_t)sbg * N_SP + n) * 16 + quad * 4) = make_uint2(u0, u1);
      }
    } else {
      #pragma unroll
      for (int c = 0; c < 4; ++c) {
        int n = nt * 64 + c * 16 + l15;
        #pragma unroll
        for (int r = 0; r < 4; ++r)
          gT[(size_t)sbg * 16 * N_SP + (size_t)(quad * 4 + r) * N_SP + n] =
              (unsigned short)f32_to_bf16_rne(acc[rt][c][r] + bv[r]);
      }
    }
  }
}

// ---------------------------------------------------------------------------
// K2: MFMA flash attention (unnormalized softmax, constant shift -8).
// mfma1 (f16): S^T = phi_tile * theta^T; S^T C-layout == A-layout of P.
// P/g in BF16 (fp32 exponent range) - no overflow, no clamp.
// Epilogue writes AT[sb][n][c] bf16 (frag-ready for wconv_mfma B-operand).
// grid = 32 sbg * 36 ntiles = 1152 x 256 (4 waves, 64 query rows/block)
// ---------------------------------------------------------------------------
__global__ __launch_bounds__(256) void attn_kernel(const _Float16* __restrict__ theta,
                                                   const _Float16* __restrict__ phi,
                                                   const unsigned short* __restrict__ gT,
                                                   unsigned short* __restrict__ attoT)
{
  __shared__ short sphi[256 * 20];   // phi chunk [m_local][16], row stride 20 halves (40 B)
  __shared__ short sgt [16 * 260];   // gT chunk [d][m_local] bf16, row stride 260 (520 B)
  __shared__ float redl[4][16];

  int bid = blockIdx.x;
  int nt  = bid % 36;
  int sbg = bid / 36;
  int g   = sbg & 7;
  int sb  = sbg >> 3;                // s*2+b

  int tid  = threadIdx.x;
  int lane = tid & 63;
  int wv   = tid >> 6;
  int l15  = lane & 15;
  int quad = lane >> 4;

  size_t base16 = (size_t)sbg * N_SP * CGD;

  // B-frag theta for this wave's 16 rows, loaded once: B[k=quad*4+j][n=l15]
  int n_row = nt*64 + wv*16 + l15;
  v4h bTheta = __builtin_bit_cast(v4h,
      *(const uint2*)(theta + base16 + (size_t)n_row*16 + quad*4));

  v4f acc = {0.f, 0.f, 0.f, 0.f};
  float lsum = 0.f;

  for (int c0 = 0; c0 < N_SP; c0 += 256) {
    __syncthreads();
    // stage phi rows c0..c0+255 (32 B per thread)
    {
      const uint4* src = (const uint4*)(phi + base16 + (size_t)(c0 + tid)*16);
      uint4 v0 = src[0], v1 = src[1];
      uint2* dst = (uint2*)((char*)sphi + tid*40);
      dst[0] = make_uint2(v0.x, v0.y); dst[1] = make_uint2(v0.z, v0.w);
      dst[2] = make_uint2(v1.x, v1.y); dst[3] = make_uint2(v1.z, v1.w);
      // stage gT: 16 rows x 256 halves (bf16 bits, bitwise copy)
      int d = tid >> 4, seg = tid & 15;
      const uint4* gs = (const uint4*)(gT + base16 + (size_t)d*N_SP + c0 + seg*16);
      uint4 g0 = gs[0], g1 = gs[1];
      uint2* gd = (uint2*)((char*)sgt + d*520 + seg*32);
      gd[0] = make_uint2(g0.x, g0.y); gd[1] = make_uint2(g0.z, g0.w);
      gd[2] = make_uint2(g1.x, g1.y); gd[3] = make_uint2(g1.z, g1.w);
    }
    __syncthreads();

    #pragma unroll 4
    for (int sub = 0; sub < 16; ++sub) {
      int mb = sub * 16;
      // A-frag phi: A[m=l15][k=quad*4+j]
      v4h aPhi = __builtin_bit_cast(v4h,
          *(const uint2*)((const char*)sphi + (size_t)(mb + l15)*40 + quad*8));
      v4f S = __builtin_amdgcn_mfma_f32_16x16x16f16(aPhi, bTheta, (v4f){0.f,0.f,0.f,0.f}, 0, 0, 0);
      // lane holds S[n=l15][m = c0+mb+quad*4+r]
      float e0 = __expf(S[0] - 8.f);
      float e1 = __expf(S[1] - 8.f);
      float e2 = __expf(S[2] - 8.f);
      float e3 = __expf(S[3] - 8.f);
      lsum += (e0 + e1) + (e2 + e3);
      unsigned lo = f32_to_bf16_rne(e0) | (f32_to_bf16_rne(e1) << 16);
      unsigned hi = f32_to_bf16_rne(e2) | (f32_to_bf16_rne(e3) << 16);
      v4s P = __builtin_bit_cast(v4s, make_uint2(lo, hi));   // A[n=l15][k=quad*4+j]
      // B-frag g (bf16): B[k=quad*4+j][d=l15] from gT chunk
      v4s gf = __builtin_bit_cast(v4s,
          *(const uint2*)((const char*)sgt + (size_t)l15*520 + (size_t)(mb + quad*4)*2));
      acc = __builtin_amdgcn_mfma_f32_16x16x16bf16_1k(P, gf, acc, 0, 0, 0);
    }
  }

  // reduce lsum across quads (lanes sharing l15)
  lsum += __shfl_xor(lsum, 16, 64);
  lsum += __shfl_xor(lsum, 32, 64);
  if (lane < 16) redl[wv][lane] = lsum;
  __syncthreads();

  // acc C-layout: row n_local = quad*4+r, col d = l15 -> AT[sb][n][g*16+d] bf16
  #pragma unroll
  for (int r2 = 0; r2 < 4; ++r2) {
    int n = nt*64 + wv*16 + quad*4 + r2;
    float ls = redl[wv][quad*4 + r2];
    attoT[((size_t)sb * N_SP + n) * INTERC + g*16 + l15] =
        (unsigned short)f32_to_bf16_rne(acc[r2] / ls);
  }
}

// ---------------------------------------------------------------------------
// K3: W 1x1 conv via MFMA: WY[o][n] = sum_c WWB[o][c] * AT[n][c] + Wb[o].
// grid = 4(sb)*36(nt of 64)*2(row half) = 288 x 256; wave tile 32 o x 64 n.
// ---------------------------------------------------------------------------
__global__ __launch_bounds__(256) void wconv_mfma(const unsigned short* __restrict__ wwb,
                                                  const unsigned short* __restrict__ attoT,
                                                  const float* __restrict__ Wb0, const float* __restrict__ Wb1,
                                                  float* __restrict__ wy)
{
  int bid = blockIdx.x;
  int nt = bid % 36;
  int rh = (bid / 36) & 1;
  int sb = bid / 72;
  int s  = sb >> 1;
  int tid = threadIdx.x, lane = tid & 63, wv = tid >> 6;
  int l15 = lane & 15, quad = lane >> 4;

  const unsigned short* A = wwb + (size_t)s * 32768;
  const unsigned short* B = attoT + (size_t)sb * N_SP * INTERC;

  v4f acc[2][4];
  #pragma unroll
  for (int rt = 0; rt < 2; ++rt)
    #pragma unroll
    for (int c = 0; c < 4; ++c) acc[rt][c] = (v4f){0.f, 0.f, 0.f, 0.f};

  #pragma unroll
  for (int k0 = 0; k0 < 128; k0 += 16) {
    v4s a[2], b[4];
    #pragma unroll
    for (int rt = 0; rt < 2; ++rt) {
      int o = rh * 128 + wv * 32 + rt * 16 + l15;
      a[rt] = __builtin_bit_cast(v4s, *(const uint2*)(A + (size_t)o * 128 + k0 + quad * 4));
    }
    #pragma unroll
    for (int c = 0; c < 4; ++c) {
      int n = nt * 64 + c * 16 + l15;
      b[c] = __builtin_bit_cast(v4s, *(const uint2*)(B + (size_t)n * 128 + k0 + quad * 4));
    }
    #pragma unroll
    for (int rt = 0; rt < 2; ++rt)
      #pragma unroll
      for (int c = 0; c < 4; ++c)
        acc[rt][c] = __builtin_amdgcn_mfma_f32_16x16x16bf16_1k(a[rt], b[c], acc[rt][c], 0, 0, 0);
  }

  const float* Wb = s ? Wb1 : Wb0;
  #pragma unroll
  for (int rt = 0; rt < 2; ++rt) {
    float bv[4];
    int ob = rh * 128 + wv * 32 + rt * 16 + quad * 4;
    #pragma unroll
    for (int r = 0; r < 4; ++r) bv[r] = Wb[ob + r];
    #pragma unroll
    for (int c = 0; c < 4; ++c) {
      int n = nt * 64 + c * 16 + l15;
      #pragma unroll
      for (int r = 0; r < 4; ++r)
        wy[((size_t)sb * CC + ob + r) * N_SP + n] = acc[rt][c][r] + bv[r];
    }
  }
}

// ---------------------------------------------------------------------------
// K4: BatchNorm (training-mode batch stats over (b,n)) + residual + ReLU.
// grid = 2(sub)*256(o) = 512 x 256. Block reduces 4608 values.
// ---------------------------------------------------------------------------
__global__ __launch_bounds__(256) void bn_kernel(const float* __restrict__ wy,
                                                 const float* __restrict__ x0, const float* __restrict__ x1,
                                                 const float* __restrict__ g0, const float* __restrict__ b0,
                                                 const float* __restrict__ g1, const float* __restrict__ b1,
                                                 float* __restrict__ out)
{
  int o = blockIdx.x % 256;
  int s = blockIdx.x / 256;
  int t = threadIdx.x;
  const float* bng = s ? g1 : g0;
  const float* bnb = s ? b1 : b0;
  const float* xin = s ? x1 : x0;

  float sum = 0.f, ssq = 0.f;
  #pragma unroll
  for (int b2 = 0; b2 < 2; ++b2) {
    const float* wyp = wy + (size_t)((s*2 + b2)*CC + o) * N_SP;
    for (int n = t; n < N_SP; n += 256) { float v = wyp[n]; sum += v; ssq = fmaf(v, v, ssq); }
  }
  #pragma unroll
  for (int off = 32; off > 0; off >>= 1) {
    sum += __shfl_down(sum, off, 64);
    ssq += __shfl_down(ssq, off, 64);
  }
  __shared__ float red[8];
  __shared__ float sc[2];
  int wid = t >> 6, lane = t & 63;
  if (lane == 0) { red[wid] = sum; red[4 + wid] = ssq; }
  __syncthreads();
  if (t == 0) {
    float S = red[0] + red[1] + red[2] + red[3];
    float Q = red[4] + red[5] + red[6] + red[7];
    float mean = S * (1.f / 4608.f);
    float var  = Q * (1.f / 4608.f) - mean * mean;
    float rstd = rsqrtf(var + 1e-5f);
    float scale = bng[o] * rstd;
    sc[0] = scale;
    sc[1] = bnb[o] - mean * scale;
  }
  __syncthreads();
  float scale = sc[0], shift = sc[1];
  #pragma unroll
  for (int b2 = 0; b2 < 2; ++b2) {
    const float* wyp = wy + (size_t)((s*2 + b2)*CC + o) * N_SP;
    const float* xp  = xin + (size_t)(b2*CC + o) * N_SP;
    float* op = out + (size_t)s * BB*CC*N_SP + (size_t)(b2*CC + o) * N_SP;
    for (int n = t; n < N_SP; n += 256) {
      float v = fmaf(wyp[n], scale, shift) + xp[n];
      op[n] = fmaxf(v, 0.f);
    }
  }
}

// ---------------------------------------------------------------------------
extern "C" void kernel_launch(void* const* d_in, const int* in_sizes, int n_in,
                              void* d_out, int out_size, void* d_ws, size_t ws_size,
                              hipStream_t stream)
{
  const float* xc = (const float*)d_in[0];
  const float* xr = (const float*)d_in[1];
  // per-sub input bases: cls=2, reg=12; order: g_w,g_b,theta_w,theta_b,phi_w,phi_b,W_w,W_b,bn_g,bn_b
  PackP pk;
  BiasP bp;
  for (int s = 0; s < 2; ++s) {
    int bs = 2 + s * 10;
    pk.src[s*3 + 0] = (const float*)d_in[bs + 2];  // theta_w
    pk.src[s*3 + 1] = (const float*)d_in[bs + 4];  // phi_w
    pk.src[s*3 + 2] = (const float*)d_in[bs + 0];  // g_w
    pk.src[6 + s]   = (const float*)d_in[bs + 6];  // W_w
    bp.b[s*3 + 0]   = (const float*)d_in[bs + 3];  // theta_b
    bp.b[s*3 + 1]   = (const float*)d_in[bs + 5];  // phi_b
    bp.b[s*3 + 2]   = (const float*)d_in[bs + 1];  // g_b
  }

  char* wsb = (char*)d_ws;
  _Float16*       XT    = (_Float16*)(wsb + OFF_XT);
  _Float16*       WH    = (_Float16*)(wsb + OFF_WH);
  unsigned short* WWB   = (unsigned short*)(wsb + OFF_WWB);
  _Float16*       THETA = (_Float16*)(wsb + OFF_TH);
  _Float16*       PHI   = (_Float16*)(wsb + OFF_PH);
  unsigned short* GT    = (unsigned short*)(wsb + OFF_GT);
  unsigned short* AT    = (unsigned short*)(wsb + OFF_AT);
  float*          WY    = (float*)(wsb + OFF_WY);

  pack_kernel<<<1024, 256, 0, stream>>>(pk, WH, WWB);
  transpose_kernel<<<576, 256, 0, stream>>>(xc, xr, XT);
  proj_mfma<<<432, 256, 0, stream>>>(bp, WH, XT, THETA, PHI, GT);
  attn_kernel<<<1152, 256, 0, stream>>>(THETA, PHI, GT, AT);
  wconv_mfma<<<288, 256, 0, stream>>>(WWB, AT,
                                      (const float*)d_in[9], (const float*)d_in[19], WY);
  bn_kernel<<<512, 256, 0, stream>>>(WY, xc, xr,
                                     (const float*)d_in[10], (const float*)d_in[11],
                                     (const float*)d_in[20], (const float*)d_in[21],
                                     (float*)d_out);
}

// Round 7
// 194.362 us; speedup vs baseline: 3.1044x; 1.1129x over previous
//
#include <hip/hip_runtime.h>
#include <math.h>

// Problem constants
#define N_SP   2304      // H*W = 48*48
#define CC     256       // C
#define GG     8         // groups
#define CGD    16        // channels per group
#define INTERC 128       // C/2
#define BB     2         // batch

#define LOG2E  1.4426950408889634f
#define CSHIFT 11.541560327111707f   // 8 * log2(e)

typedef _Float16 v4h __attribute__((ext_vector_type(4)));
typedef short    v4s __attribute__((ext_vector_type(4)));
typedef float    v4f __attribute__((ext_vector_type(4)));

__device__ inline unsigned f32_to_bf16_rne(float f) {
  unsigned u = __builtin_bit_cast(unsigned, f);
  return (u + 0x7FFFu + ((u >> 16) & 1u)) >> 16;
}

// ws layout (bytes)
// XT:   [sb=4][n=2304][c=256] f16 (x transposed)      4,718,592
// WH:   [s*3+proj][128 rows][256] f16 packed            393,216
// WWB:  [s][256 o][128 c] bf16 packed                   131,072
// THETA/PHI: [sbg=32][n=2304][16] f16                 2,359,296 each
// GT:   [sbg=32][d=16][m=2304] bf16                   2,359,296
// AT:   [sb=4][n=2304][c=128] bf16 (attn out, n-major) 2,359,296
// WY:   [sb=4][o=256][n=2304] f32                     9,437,184
#define OFF_XT   0
#define OFF_WH   4718592
#define OFF_WWB  5111808
#define OFF_TH   5242880
#define OFF_PH   7602176
#define OFF_GT   9961472
#define OFF_AT   12320768
#define OFF_WY   14680064

struct PackP { const float* src[8]; };   // 0..5: proj weights (s*3+proj), 6..7: W_w per s
struct BiasP { const float* b[6]; };     // s*3+proj

// ---------------------------------------------------------------------------
// K0: prep = pack weights (blocks 0..1023) + transpose x (blocks 1024..1599).
// theta weights (segs 0,3) pre-scaled by log2(e) so attn scores are in the
// exp2 domain (saves a v_mul per score in the attn hot loop).
// ---------------------------------------------------------------------------
__global__ __launch_bounds__(256) void prep_kernel(PackP p, _Float16* __restrict__ wh,
                                                   unsigned short* __restrict__ wwb,
                                                   const float* __restrict__ x0,
                                                   const float* __restrict__ x1,
                                                   _Float16* __restrict__ xt)
{
  int bid = blockIdx.x;
  if (bid < 1024) {
    int seg = bid >> 7;                              // 0..7
    int i = ((bid & 127) << 8) | threadIdx.x;        // 0..32767
    float v = p.src[seg][i];
    if (seg < 6) {
      if (seg == 0 || seg == 3) v *= LOG2E;          // theta
      wh[seg * 32768 + i] = (_Float16)v;
    } else {
      wwb[(seg - 6) * 32768 + i] = (unsigned short)f32_to_bf16_rne(v);
    }
    return;
  }
  // transpose path
  __shared__ float ld[64][65];
  int b2 = bid - 1024;
  int ct = b2 & 3;
  int nt = (b2 >> 2) % 36;
  int sb = b2 / 144;
  const float* src = ((sb >> 1) ? x1 : x0) + (size_t)(sb & 1) * CC * N_SP;
  int t = threadIdx.x;
  int col = t & 63, rq = t >> 6;
  #pragma unroll
  for (int i = 0; i < 16; ++i) {
    int row = i * 4 + rq;
    ld[row][col] = src[(size_t)(ct * 64 + row) * N_SP + nt * 64 + col];
  }
  __syncthreads();
  int nl = t >> 2, cs = (t & 3) * 16;
  float v[16];
  #pragma unroll
  for (int j = 0; j < 16; ++j) v[j] = ld[cs + j][nl];
  unsigned u[8];
  #pragma unroll
  for (int j = 0; j < 8; ++j)
    u[j] = __builtin_bit_cast(unsigned, __builtin_amdgcn_cvt_pkrtz(v[2*j], v[2*j+1]));
  _Float16* dst = xt + ((size_t)sb * N_SP + nt * 64 + nl) * 256 + ct * 64 + cs;
  uint4* d4 = (uint4*)dst;
  d4[0] = make_uint4(u[0], u[1], u[2], u[3]);
  d4[1] = make_uint4(u[4], u[5], u[6], u[7]);
}

// ---------------------------------------------------------------------------
// K1: proj via MFMA. Per (sb, proj): O[128 rows][2304 n] = WH[128][256] * X.
// grid = 4(sb)*3(proj)*36(nt of 64) = 432 x 256; wave tile 32 rows x 64 n.
// ---------------------------------------------------------------------------
__global__ __launch_bounds__(256) void proj_mfma(BiasP bp, const _Float16* __restrict__ wh,
                                                 const _Float16* __restrict__ xt,
                                                 _Float16* __restrict__ theta, _Float16* __restrict__ phi,
                                                 unsigned short* __restrict__ gT)
{
  int bid = blockIdx.x;
  int nt   = bid % 36;
  int proj = (bid / 36) % 3;
  int sb   = bid / 108;
  int s    = sb >> 1;
  int tid = threadIdx.x, lane = tid & 63, wv = tid >> 6;
  int l15 = lane & 15, quad = lane >> 4;

  const _Float16* A = wh + (size_t)(s * 3 + proj) * 32768;
  const _Float16* B = xt + (size_t)sb * N_SP * 256;

  v4f acc[2][4];
  #pragma unroll
  for (int rt = 0; rt < 2; ++rt)
    #pragma unroll
    for (int c = 0; c < 4; ++c) acc[rt][c] = (v4f){0.f, 0.f, 0.f, 0.f};

  #pragma unroll 2
  for (int k0 = 0; k0 < 256; k0 += 16) {
    v4h a[2], b[4];
    #pragma unroll
    for (int rt = 0; rt < 2; ++rt) {
      int row = wv * 32 + rt * 16 + l15;
      a[rt] = __builtin_bit_cast(v4h, *(const uint2*)(A + (size_t)row * 256 + k0 + quad * 4));
    }
    #pragma unroll
    for (int c = 0; c < 4; ++c) {
      int n = nt * 64 + c * 16 + l15;
      b[c] = __builtin_bit_cast(v4h, *(const uint2*)(B + (size_t)n * 256 + k0 + quad * 4));
    }
    #pragma unroll
    for (int rt = 0; rt < 2; ++rt)
      #pragma unroll
      for (int c = 0; c < 4; ++c)
        acc[rt][c] = __builtin_amdgcn_mfma_f32_16x16x16f16(a[rt], b[c], acc[rt][c], 0, 0, 0);
  }

  const float* bias = bp.b[s * 3 + proj];
  float bscale = (proj == 0) ? LOG2E : 1.0f;   // theta bias also in log2 domain
  #pragma unroll
  for (int rt = 0; rt < 2; ++rt) {
    int g   = wv * 2 + rt;            // row tile == group (rows = g*16+d)
    int sbg = sb * 8 + g;
    float bv[4];
    #pragma unroll
    for (int r = 0; r < 4; ++r) bv[r] = bias[g * 16 + quad * 4 + r] * bscale;
    if (proj < 2) {
      _Float16* outp = (proj == 0 ? theta : phi);
      #pragma unroll
      for (int c = 0; c < 4; ++c) {
        int n = nt * 64 + c * 16 + l15;
        unsigned u0 = __builtin_bit_cast(unsigned,
            __builtin_amdgcn_cvt_pkrtz(acc[rt][c][0] + bv[0], acc[rt][c][1] + bv[1]));
        unsigned u1 = __builtin_bit_cast(unsigned,
            __builtin_amdgcn_cvt_pkrtz(acc[rt][c][2] + bv[2], acc[rt][c][3] + bv[3]));
        *(uint2*)(outp + ((size_t)sbg * N_SP + n) * 16 + quad * 4) = make_uint2(u0, u1);
      }
    } else {
      #pragma unroll
      for (int c = 0; c < 4; ++c) {
        int n = nt * 64 + c * 16 + l15;
        #pragma unroll
        for (int r = 0; r < 4; ++r)
          gT[(size_t)sbg * 16 * N_SP + (size_t)(quad * 4 + r) * N_SP + n] =
              (unsigned short)f32_to_bf16_rne(acc[rt][c][r] + bv[r]);
      }
    }
  }
}

// ---------------------------------------------------------------------------
// K2: MFMA flash attention, scores in exp2 domain (theta pre-scaled by log2e).
// mfma1 (f16): S^T = phi_tile * theta^T + Cinit(-8*log2e)  <- shift folded in.
// e = exp2(S) directly (v_exp_f32). P packed to bf16 via 1 v_perm (truncation).
// sgt staging XOR-swizzled: granule g stored at g^((g>>4)&3) -> write quarter
// covers all 16 bank-pairs (kills the 1.99M SQ_LDS_BANK_CONFLICT).
// grid = 32 sbg * 36 ntiles = 1152 x 256 (4 waves, 64 query rows/block)
// ---------------------------------------------------------------------------
__global__ __launch_bounds__(256) void attn_kernel(const _Float16* __restrict__ theta,
                                                   const _Float16* __restrict__ phi,
                                                   const unsigned short* __restrict__ gT,
                                                   unsigned short* __restrict__ attoT)
{
  __shared__ short sphi[256 * 20];   // phi chunk [m_local][16], row stride 40 B
  __shared__ short sgt [16 * 260];   // gT chunk [d][granules swizzled], row stride 520 B
  __shared__ float redl[4][16];

  int bid = blockIdx.x;
  int nt  = bid % 36;
  int sbg = bid / 36;
  int g   = sbg & 7;
  int sb  = sbg >> 3;                // s*2+b

  int tid  = threadIdx.x;
  int lane = tid & 63;
  int wv   = tid >> 6;
  int l15  = lane & 15;
  int quad = lane >> 4;

  size_t base16 = (size_t)sbg * N_SP * CGD;

  // B-frag theta for this wave's 16 rows, loaded once: B[k=quad*4+j][n=l15]
  int n_row = nt*64 + wv*16 + l15;
  v4h bTheta = __builtin_bit_cast(v4h,
      *(const uint2*)(theta + base16 + (size_t)n_row*16 + quad*4));

  const v4f Cinit = {-CSHIFT, -CSHIFT, -CSHIFT, -CSHIFT};
  v4f acc = {0.f, 0.f, 0.f, 0.f};
  float lsum = 0.f;

  for (int c0 = 0; c0 < N_SP; c0 += 256) {
    __syncthreads();
    // stage phi rows c0..c0+255 (32 B per thread)
    {
      const uint4* src = (const uint4*)(phi + base16 + (size_t)(c0 + tid)*16);
      uint4 v0 = src[0], v1 = src[1];
      uint2* dst = (uint2*)((char*)sphi + tid*40);
      dst[0] = make_uint2(v0.x, v0.y); dst[1] = make_uint2(v0.z, v0.w);
      dst[2] = make_uint2(v1.x, v1.y); dst[3] = make_uint2(v1.z, v1.w);
      // stage gT: 16 rows x 256 halves, granule-swizzled
      int d = tid >> 4, seg = tid & 15, s2 = seg >> 2;
      const uint4* gs = (const uint4*)(gT + base16 + (size_t)d*N_SP + c0 + seg*16);
      uint4 g0 = gs[0], g1 = gs[1];
      char* rowp = (char*)sgt + d*520;
      *(uint2*)(rowp + (((seg*4 + 0) ^ s2) * 8)) = make_uint2(g0.x, g0.y);
      *(uint2*)(rowp + (((seg*4 + 1) ^ s2) * 8)) = make_uint2(g0.z, g0.w);
      *(uint2*)(rowp + (((seg*4 + 2) ^ s2) * 8)) = make_uint2(g1.x, g1.y);
      *(uint2*)(rowp + (((seg*4 + 3) ^ s2) * 8)) = make_uint2(g1.z, g1.w);
    }
    __syncthreads();

    #pragma unroll
    for (int sub = 0; sub < 16; ++sub) {
      int mb = sub * 16;
      // A-frag phi: A[m=l15][k=quad*4+j]
      v4h aPhi = __builtin_bit_cast(v4h,
          *(const uint2*)((const char*)sphi + (size_t)(mb + l15)*40 + quad*8));
      v4f S = __builtin_amdgcn_mfma_f32_16x16x16f16(aPhi, bTheta, Cinit, 0, 0, 0);
      // lane holds S[n=l15][m = c0+mb+quad*4+r], already log2-domain + shift
      float e0 = __builtin_amdgcn_exp2f(S[0]);
      float e1 = __builtin_amdgcn_exp2f(S[1]);
      float e2 = __builtin_amdgcn_exp2f(S[2]);
      float e3 = __builtin_amdgcn_exp2f(S[3]);
      lsum += (e0 + e1) + (e2 + e3);
      unsigned lo = __builtin_amdgcn_perm(__builtin_bit_cast(unsigned, e1),
                                          __builtin_bit_cast(unsigned, e0), 0x07060302u);
      unsigned hi = __builtin_amdgcn_perm(__builtin_bit_cast(unsigned, e3),
                                          __builtin_bit_cast(unsigned, e2), 0x07060302u);
      v4s P = __builtin_bit_cast(v4s, make_uint2(lo, hi));   // A[n=l15][k=quad*4+j]
      // B-frag g (bf16): B[k=quad*4+j][d=l15], swizzled granule read
      int kk = (sub >> 2) & 3;
      v4s gf = __builtin_bit_cast(v4s,
          *(const uint2*)((const char*)sgt + (size_t)l15*520 + sub*32 + ((quad ^ kk) * 8)));
      acc = __builtin_amdgcn_mfma_f32_16x16x16bf16_1k(P, gf, acc, 0, 0, 0);
    }
  }

  // reduce lsum across quads (lanes sharing l15)
  lsum += __shfl_xor(lsum, 16, 64);
  lsum += __shfl_xor(lsum, 32, 64);
  if (lane < 16) redl[wv][lane] = lsum;
  __syncthreads();

  // acc C-layout: row n_local = quad*4+r, col d = l15 -> AT[sb][n][g*16+d] bf16
  #pragma unroll
  for (int r2 = 0; r2 < 4; ++r2) {
    int n = nt*64 + wv*16 + quad*4 + r2;
    float ls = redl[wv][quad*4 + r2];
    attoT[((size_t)sb * N_SP + n) * INTERC + g*16 + l15] =
        (unsigned short)f32_to_bf16_rne(acc[r2] / ls);
  }
}

// ---------------------------------------------------------------------------
// K3: W 1x1 conv via MFMA: WY[o][n] = sum_c WWB[o][c] * AT[n][c] + Wb[o].
// grid = 4(sb)*36(nt of 64)*2(row half) = 288 x 256; wave tile 32 o x 64 n.
// ---------------------------------------------------------------------------
__global__ __launch_bounds__(256) void wconv_mfma(const unsigned short* __restrict__ wwb,
                                                  const unsigned short* __restrict__ attoT,
                                                  const float* __restrict__ Wb0, const float* __restrict__ Wb1,
                                                  float* __restrict__ wy)
{
  int bid = blockIdx.x;
  int nt = bid % 36;
  int rh = (bid / 36) & 1;
  int sb = bid / 72;
  int s  = sb >> 1;
  int tid = threadIdx.x, lane = tid & 63, wv = tid >> 6;
  int l15 = lane & 15, quad = lane >> 4;

  const unsigned short* A = wwb + (size_t)s * 32768;
  const unsigned short* B = attoT + (size_t)sb * N_SP * INTERC;

  v4f acc[2][4];
  #pragma unroll
  for (int rt = 0; rt < 2; ++rt)
    #pragma unroll
    for (int c = 0; c < 4; ++c) acc[rt][c] = (v4f){0.f, 0.f, 0.f, 0.f};

  #pragma unroll
  for (int k0 = 0; k0 < 128; k0 += 16) {
    v4s a[2], b[4];
    #pragma unroll
    for (int rt = 0; rt < 2; ++rt) {
      int o = rh * 128 + wv * 32 + rt * 16 + l15;
      a[rt] = __builtin_bit_cast(v4s, *(const uint2*)(A + (size_t)o * 128 + k0 + quad * 4));
    }
    #pragma unroll
    for (int c = 0; c < 4; ++c) {
      int n = nt * 64 + c * 16 + l15;
      b[c] = __builtin_bit_cast(v4s, *(const uint2*)(B + (size_t)n * 128 + k0 + quad * 4));
    }
    #pragma unroll
    for (int rt = 0; rt < 2; ++rt)
      #pragma unroll
      for (int c = 0; c < 4; ++c)
        acc[rt][c] = __builtin_amdgcn_mfma_f32_16x16x16bf16_1k(a[rt], b[c], acc[rt][c], 0, 0, 0);
  }

  const float* Wb = s ? Wb1 : Wb0;
  #pragma unroll
  for (int rt = 0; rt < 2; ++rt) {
    float bv[4];
    int ob = rh * 128 + wv * 32 + rt * 16 + quad * 4;
    #pragma unroll
    for (int r = 0; r < 4; ++r) bv[r] = Wb[ob + r];
    #pragma unroll
    for (int c = 0; c < 4; ++c) {
      int n = nt * 64 + c * 16 + l15;
      #pragma unroll
      for (int r = 0; r < 4; ++r)
        wy[((size_t)sb * CC + ob + r) * N_SP + n] = acc[rt][c][r] + bv[r];
    }
  }
}

// ---------------------------------------------------------------------------
// K4: BatchNorm (training-mode batch stats over (b,n)) + residual + ReLU.
// grid = 2(sub)*256(o) = 512 x 256. Block reduces 4608 values.
// ---------------------------------------------------------------------------
__global__ __launch_bounds__(256) void bn_kernel(const float* __restrict__ wy,
                                                 const float* __restrict__ x0, const float* __restrict__ x1,
                                                 const float* __restrict__ g0, const float* __restrict__ b0,
                                                 const float* __restrict__ g1, const float* __restrict__ b1,
                                                 float* __restrict__ out)
{
  int o = blockIdx.x % 256;
  int s = blockIdx.x / 256;
  int t = threadIdx.x;
  const float* bng = s ? g1 : g0;
  const float* bnb = s ? b1 : b0;
  const float* xin = s ? x1 : x0;

  float sum = 0.f, ssq = 0.f;
  #pragma unroll
  for (int b2 = 0; b2 < 2; ++b2) {
    const float* wyp = wy + (size_t)((s*2 + b2)*CC + o) * N_SP;
    for (int n = t; n < N_SP; n += 256) { float v = wyp[n]; sum += v; ssq = fmaf(v, v, ssq); }
  }
  #pragma unroll
  for (int off = 32; off > 0; off >>= 1) {
    sum += __shfl_down(sum, off, 64);
    ssq += __shfl_down(ssq, off, 64);
  }
  __shared__ float red[8];
  __shared__ float sc[2];
  int wid = t >> 6, lane = t & 63;
  if (lane == 0) { red[wid] = sum; red[4 + wid] = ssq; }
  __syncthreads();
  if (t == 0) {
    float S = red[0] + red[1] + red[2] + red[3];
    float Q = red[4] + red[5] + red[6] + red[7];
    float mean = S * (1.f / 4608.f);
    float var  = Q * (1.f / 4608.f) - mean * mean;
    float rstd = rsqrtf(var + 1e-5f);
    float scale = bng[o] * rstd;
    sc[0] = scale;
    sc[1] = bnb[o] - mean * scale;
  }
  __syncthreads();
  float scale = sc[0], shift = sc[1];
  #pragma unroll
  for (int b2 = 0; b2 < 2; ++b2) {
    const float* wyp = wy + (size_t)((s*2 + b2)*CC + o) * N_SP;
    const float* xp  = xin + (size_t)(b2*CC + o) * N_SP;
    float* op = out + (size_t)s * BB*CC*N_SP + (size_t)(b2*CC + o) * N_SP;
    for (int n = t; n < N_SP; n += 256) {
      float v = fmaf(wyp[n], scale, shift) + xp[n];
      op[n] = fmaxf(v, 0.f);
    }
  }
}

// ---------------------------------------------------------------------------
extern "C" void kernel_launch(void* const* d_in, const int* in_sizes, int n_in,
                              void* d_out, int out_size, void* d_ws, size_t ws_size,
                              hipStream_t stream)
{
  const float* xc = (const float*)d_in[0];
  const float* xr = (const float*)d_in[1];
  // per-sub input bases: cls=2, reg=12; order: g_w,g_b,theta_w,theta_b,phi_w,phi_b,W_w,W_b,bn_g,bn_b
  PackP pk;
  BiasP bp;
  for (int s = 0; s < 2; ++s) {
    int bs = 2 + s * 10;
    pk.src[s*3 + 0] = (const float*)d_in[bs + 2];  // theta_w
    pk.src[s*3 + 1] = (const float*)d_in[bs + 4];  // phi_w
    pk.src[s*3 + 2] = (const float*)d_in[bs + 0];  // g_w
    pk.src[6 + s]   = (const float*)d_in[bs + 6];  // W_w
    bp.b[s*3 + 0]   = (const float*)d_in[bs + 3];  // theta_b
    bp.b[s*3 + 1]   = (const float*)d_in[bs + 5];  // phi_b
    bp.b[s*3 + 2]   = (const float*)d_in[bs + 1];  // g_b
  }

  char* wsb = (char*)d_ws;
  _Float16*       XT    = (_Float16*)(wsb + OFF_XT);
  _Float16*       WH    = (_Float16*)(wsb + OFF_WH);
  unsigned short* WWB   = (unsigned short*)(wsb + OFF_WWB);
  _Float16*       THETA = (_Float16*)(wsb + OFF_TH);
  _Float16*       PHI   = (_Float16*)(wsb + OFF_PH);
  unsigned short* GT    = (unsigned short*)(wsb + OFF_GT);
  unsigned short* AT    = (unsigned short*)(wsb + OFF_AT);
  float*          WY    = (float*)(wsb + OFF_WY);

  prep_kernel<<<1600, 256, 0, stream>>>(pk, WH, WWB, xc, xr, XT);
  proj_mfma<<<432, 256, 0, stream>>>(bp, WH, XT, THETA, PHI, GT);
  attn_kernel<<<1152, 256, 0, stream>>>(THETA, PHI, GT, AT);
  wconv_mfma<<<288, 256, 0, stream>>>(WWB, AT,
                                      (const float*)d_in[9], (const float*)d_in[19], WY);
  bn_kernel<<<512, 256, 0, stream>>>(WY, xc, xr,
                                     (const float*)d_in[10], (const float*)d_in[11],
                                     (const float*)d_in[20], (const float*)d_in[21],
                                     (float*)d_out);
}

// Round 8
// 191.901 us; speedup vs baseline: 3.1443x; 1.0128x over previous
//
#include <hip/hip_runtime.h>
#include <math.h>

// Problem constants
#define N_SP   2304      // H*W = 48*48
#define CC     256       // C
#define GG     8         // groups
#define CGD    16        // channels per group
#define INTERC 128       // C/2
#define BB     2         // batch

#define LOG2E  1.4426950408889634f
#define CSHIFT 11.541560327111707f   // 8 * log2(e)

typedef _Float16 v4h __attribute__((ext_vector_type(4)));
typedef short    v4s __attribute__((ext_vector_type(4)));
typedef float    v4f __attribute__((ext_vector_type(4)));

__device__ inline unsigned f32_to_bf16_rne(float f) {
  unsigned u = __builtin_bit_cast(unsigned, f);
  return (u + 0x7FFFu + ((u >> 16) & 1u)) >> 16;
}

// ws layout (bytes)
// XT:   [sb=4][n=2304][c=256] f16 (x transposed)      4,718,592
// WH:   [s*3+proj][128 rows][256] f16 packed            393,216
// WWB:  [s][256 o][128 c] bf16 packed                   131,072
// THETA/PHI: [sbg=32][n=2304][16] f16                 2,359,296 each
// GT:   [sbg=32][d=16][m=2304] bf16                   2,359,296
// AT:   [sb=4][n=2304][c=128] bf16 (attn out, n-major) 2,359,296
// WY:   [sb=4][o=256][n=2304] f32                     9,437,184
// STATS:[s=2][2][256] f32 (sum, sumsq)                     4,096
#define OFF_XT    0
#define OFF_WH    4718592
#define OFF_WWB   5111808
#define OFF_TH    5242880
#define OFF_PH    7602176
#define OFF_GT    9961472
#define OFF_AT    12320768
#define OFF_WY    14680064
#define OFF_STATS 24117248

struct PackP { const float* src[8]; };   // 0..5: proj weights (s*3+proj), 6..7: W_w per s
struct BiasP { const float* b[6]; };     // s*3+proj

// ---------------------------------------------------------------------------
// K0: prep = pack weights (blocks 0..1023) + transpose x (1024..1599) +
// zero the stats buffer (block 1600). theta weights pre-scaled by log2(e).
// ---------------------------------------------------------------------------
__global__ __launch_bounds__(256) void prep_kernel(PackP p, _Float16* __restrict__ wh,
                                                   unsigned short* __restrict__ wwb,
                                                   const float* __restrict__ x0,
                                                   const float* __restrict__ x1,
                                                   _Float16* __restrict__ xt,
                                                   float* __restrict__ stats)
{
  int bid = blockIdx.x;
  if (bid == 1600) {
    ((float4*)stats)[threadIdx.x] = make_float4(0.f, 0.f, 0.f, 0.f);
    return;
  }
  if (bid < 1024) {
    int seg = bid >> 7;                              // 0..7
    int i = ((bid & 127) << 8) | threadIdx.x;        // 0..32767
    float v = p.src[seg][i];
    if (seg < 6) {
      if (seg == 0 || seg == 3) v *= LOG2E;          // theta
      wh[seg * 32768 + i] = (_Float16)v;
    } else {
      wwb[(seg - 6) * 32768 + i] = (unsigned short)f32_to_bf16_rne(v);
    }
    return;
  }
  // transpose path
  __shared__ float ld[64][65];
  int b2 = bid - 1024;
  int ct = b2 & 3;
  int nt = (b2 >> 2) % 36;
  int sb = b2 / 144;
  const float* src = ((sb >> 1) ? x1 : x0) + (size_t)(sb & 1) * CC * N_SP;
  int t = threadIdx.x;
  int col = t & 63, rq = t >> 6;
  #pragma unroll
  for (int i = 0; i < 16; ++i) {
    int row = i * 4 + rq;
    ld[row][col] = src[(size_t)(ct * 64 + row) * N_SP + nt * 64 + col];
  }
  __syncthreads();
  int nl = t >> 2, cs = (t & 3) * 16;
  float v[16];
  #pragma unroll
  for (int j = 0; j < 16; ++j) v[j] = ld[cs + j][nl];
  unsigned u[8];
  #pragma unroll
  for (int j = 0; j < 8; ++j)
    u[j] = __builtin_bit_cast(unsigned, __builtin_amdgcn_cvt_pkrtz(v[2*j], v[2*j+1]));
  _Float16* dst = xt + ((size_t)sb * N_SP + nt * 64 + nl) * 256 + ct * 64 + cs;
  uint4* d4 = (uint4*)dst;
  d4[0] = make_uint4(u[0], u[1], u[2], u[3]);
  d4[1] = make_uint4(u[4], u[5], u[6], u[7]);
}

// ---------------------------------------------------------------------------
// K1: proj via MFMA. Per (sb, proj): O[128 rows][2304 n] = WH[128][256] * X.
// grid = 4(sb)*3(proj)*36(nt of 64) = 432 x 256; wave tile 32 rows x 64 n.
// ---------------------------------------------------------------------------
__global__ __launch_bounds__(256) void proj_mfma(BiasP bp, const _Float16* __restrict__ wh,
                                                 const _Float16* __restrict__ xt,
                                                 _Float16* __restrict__ theta, _Float16* __restrict__ phi,
                                                 unsigned short* __restrict__ gT)
{
  int bid = blockIdx.x;
  int nt   = bid % 36;
  int proj = (bid / 36) % 3;
  int sb   = bid / 108;
  int s    = sb >> 1;
  int tid = threadIdx.x, lane = tid & 63, wv = tid >> 6;
  int l15 = lane & 15, quad = lane >> 4;

  const _Float16* A = wh + (size_t)(s * 3 + proj) * 32768;
  const _Float16* B = xt + (size_t)sb * N_SP * 256;

  v4f acc[2][4];
  #pragma unroll
  for (int rt = 0; rt < 2; ++rt)
    #pragma unroll
    for (int c = 0; c < 4; ++c) acc[rt][c] = (v4f){0.f, 0.f, 0.f, 0.f};

  #pragma unroll 2
  for (int k0 = 0; k0 < 256; k0 += 16) {
    v4h a[2], b[4];
    #pragma unroll
    for (int rt = 0; rt < 2; ++rt) {
      int row = wv * 32 + rt * 16 + l15;
      a[rt] = __builtin_bit_cast(v4h, *(const uint2*)(A + (size_t)row * 256 + k0 + quad * 4));
    }
    #pragma unroll
    for (int c = 0; c < 4; ++c) {
      int n = nt * 64 + c * 16 + l15;
      b[c] = __builtin_bit_cast(v4h, *(const uint2*)(B + (size_t)n * 256 + k0 + quad * 4));
    }
    #pragma unroll
    for (int rt = 0; rt < 2; ++rt)
      #pragma unroll
      for (int c = 0; c < 4; ++c)
        acc[rt][c] = __builtin_amdgcn_mfma_f32_16x16x16f16(a[rt], b[c], acc[rt][c], 0, 0, 0);
  }

  const float* bias = bp.b[s * 3 + proj];
  float bscale = (proj == 0) ? LOG2E : 1.0f;   // theta bias also in log2 domain
  #pragma unroll
  for (int rt = 0; rt < 2; ++rt) {
    int g   = wv * 2 + rt;            // row tile == group (rows = g*16+d)
    int sbg = sb * 8 + g;
    float bv[4];
    #pragma unroll
    for (int r = 0; r < 4; ++r) bv[r] = bias[g * 16 + quad * 4 + r] * bscale;
    if (proj < 2) {
      _Float16* outp = (proj == 0 ? theta : phi);
      #pragma unroll
      for (int c = 0; c < 4; ++c) {
        int n = nt * 64 + c * 16 + l15;
        unsigned u0 = __builtin_bit_cast(unsigned,
            __builtin_amdgcn_cvt_pkrtz(acc[rt][c][0] + bv[0], acc[rt][c][1] + bv[1]));
        unsigned u1 = __builtin_bit_cast(unsigned,
            __builtin_amdgcn_cvt_pkrtz(acc[rt][c][2] + bv[2], acc[rt][c][3] + bv[3]));
        *(uint2*)(outp + ((size_t)sbg * N_SP + n) * 16 + quad * 4) = make_uint2(u0, u1);
      }
    } else {
      #pragma unroll
      for (int c = 0; c < 4; ++c) {
        int n = nt * 64 + c * 16 + l15;
        #pragma unroll
        for (int r = 0; r < 4; ++r)
          gT[(size_t)sbg * 16 * N_SP + (size_t)(quad * 4 + r) * N_SP + n] =
              (unsigned short)f32_to_bf16_rne(acc[rt][c][r] + bv[r]);
      }
    }
  }
}

// ---------------------------------------------------------------------------
// K2: MFMA flash attention, exp2-domain scores, shift folded into MFMA C.
// 512-thread blocks (8 waves, 128 query rows): staging traffic and barriers
// per score HALVED vs the 4-wave version. sgt granule XOR-swizzle keeps
// SQ_LDS_BANK_CONFLICT at 0. grid = 32 sbg * 18 nt = 576 x 512.
// ---------------------------------------------------------------------------
__global__ __launch_bounds__(512) void attn_kernel(const _Float16* __restrict__ theta,
                                                   const _Float16* __restrict__ phi,
                                                   const unsigned short* __restrict__ gT,
                                                   unsigned short* __restrict__ attoT)
{
  __shared__ short sphi[256 * 20];   // phi chunk [m_local][16], row stride 40 B
  __shared__ short sgt [16 * 260];   // gT chunk [d][granules swizzled], row stride 520 B
  __shared__ float redl[8][16];

  int bid = blockIdx.x;
  int nt  = bid % 18;
  int sbg = bid / 18;
  int g   = sbg & 7;
  int sb  = sbg >> 3;                // s*2+b

  int tid  = threadIdx.x;            // 0..511
  int lane = tid & 63;
  int wv   = tid >> 6;               // 0..7
  int l15  = lane & 15;
  int quad = lane >> 4;

  size_t base16 = (size_t)sbg * N_SP * CGD;

  // B-frag theta for this wave's 16 rows, loaded once: B[k=quad*4+j][n=l15]
  int n_row = nt*128 + wv*16 + l15;
  v4h bTheta = __builtin_bit_cast(v4h,
      *(const uint2*)(theta + base16 + (size_t)n_row*16 + quad*4));

  const v4f Cinit = {-CSHIFT, -CSHIFT, -CSHIFT, -CSHIFT};
  v4f acc = {0.f, 0.f, 0.f, 0.f};
  float lsum = 0.f;

  // staging indices (computed once)
  int prow = tid >> 1, phalf = tid & 1;
  int gd = (tid & 255) >> 4, gseg = tid & 15, gk2 = (tid >> 8) * 2, gs2 = gseg >> 2;

  for (int c0 = 0; c0 < N_SP; c0 += 256) {
    __syncthreads();
    {
      // phi: 256 rows x 32B; each thread stages 16B of one row
      uint4 v = *((const uint4*)(phi + base16 + (size_t)(c0 + prow)*16) + phalf);
      uint2* dst = (uint2*)((char*)sphi + prow*40 + phalf*16);
      dst[0] = make_uint2(v.x, v.y); dst[1] = make_uint2(v.z, v.w);
      // gT: 16 d x 512B; each thread stages 2 swizzled 8B granules
      uint4 gv = *(const uint4*)(gT + base16 + (size_t)gd*N_SP + c0 + gseg*16 + gk2*4);
      char* rowp = (char*)sgt + gd*520;
      *(uint2*)(rowp + (((gseg*4 + gk2 + 0) ^ gs2) * 8)) = make_uint2(gv.x, gv.y);
      *(uint2*)(rowp + (((gseg*4 + gk2 + 1) ^ gs2) * 8)) = make_uint2(gv.z, gv.w);
    }
    __syncthreads();

    #pragma unroll
    for (int sub = 0; sub < 16; ++sub) {
      int mb = sub * 16;
      // A-frag phi: A[m=l15][k=quad*4+j]
      v4h aPhi = __builtin_bit_cast(v4h,
          *(const uint2*)((const char*)sphi + (size_t)(mb + l15)*40 + quad*8));
      v4f S = __builtin_amdgcn_mfma_f32_16x16x16f16(aPhi, bTheta, Cinit, 0, 0, 0);
      // lane holds S[n=l15][m = c0+mb+quad*4+r], log2-domain incl. shift
      float e0 = __builtin_amdgcn_exp2f(S[0]);
      float e1 = __builtin_amdgcn_exp2f(S[1]);
      float e2 = __builtin_amdgcn_exp2f(S[2]);
      float e3 = __builtin_amdgcn_exp2f(S[3]);
      lsum += (e0 + e1) + (e2 + e3);
      unsigned lo = __builtin_amdgcn_perm(__builtin_bit_cast(unsigned, e1),
                                          __builtin_bit_cast(unsigned, e0), 0x07060302u);
      unsigned hi = __builtin_amdgcn_perm(__builtin_bit_cast(unsigned, e3),
                                          __builtin_bit_cast(unsigned, e2), 0x07060302u);
      v4s P = __builtin_bit_cast(v4s, make_uint2(lo, hi));   // A[n=l15][k=quad*4+j]
      // B-frag g (bf16): B[k=quad*4+j][d=l15], swizzled granule read
      int kk = (sub >> 2) & 3;
      v4s gf = __builtin_bit_cast(v4s,
          *(const uint2*)((const char*)sgt + (size_t)l15*520 + sub*32 + ((quad ^ kk) * 8)));
      acc = __builtin_amdgcn_mfma_f32_16x16x16bf16_1k(P, gf, acc, 0, 0, 0);
    }
  }

  // reduce lsum across quads (lanes sharing l15)
  lsum += __shfl_xor(lsum, 16, 64);
  lsum += __shfl_xor(lsum, 32, 64);
  if (lane < 16) redl[wv][lane] = lsum;
  __syncthreads();

  // acc C-layout: row n_local = quad*4+r, col d = l15 -> AT[sb][n][g*16+d] bf16
  #pragma unroll
  for (int r2 = 0; r2 < 4; ++r2) {
    int n = nt*128 + wv*16 + quad*4 + r2;
    float ls = redl[wv][quad*4 + r2];
    attoT[((size_t)sb * N_SP + n) * INTERC + g*16 + l15] =
        (unsigned short)f32_to_bf16_rne(acc[r2] / ls);
  }
}

// ---------------------------------------------------------------------------
// K3: W 1x1 conv via MFMA + fused BN-stats accumulation (atomicAdd).
// WY[o][n] = sum_c WWB[o][c] * AT[n][c] + Wb[o];
// stats[s][0][o] += sum_n wy, stats[s][1][o] += sum_n wy^2 (this block's n).
// grid = 4(sb)*36(nt)*2(rh) = 288 x 256; wave tile 32 o x 64 n.
// ---------------------------------------------------------------------------
__global__ __launch_bounds__(256) void wconv_mfma(const unsigned short* __restrict__ wwb,
                                                  const unsigned short* __restrict__ attoT,
                                                  const float* __restrict__ Wb0, const float* __restrict__ Wb1,
                                                  float* __restrict__ wy, float* __restrict__ stats)
{
  int bid = blockIdx.x;
  int nt = bid % 36;
  int rh = (bid / 36) & 1;
  int sb = bid / 72;
  int s  = sb >> 1;
  int tid = threadIdx.x, lane = tid & 63, wv = tid >> 6;
  int l15 = lane & 15, quad = lane >> 4;

  const unsigned short* A = wwb + (size_t)s * 32768;
  const unsigned short* B = attoT + (size_t)sb * N_SP * INTERC;

  v4f acc[2][4];
  #pragma unroll
  for (int rt = 0; rt < 2; ++rt)
    #pragma unroll
    for (int c = 0; c < 4; ++c) acc[rt][c] = (v4f){0.f, 0.f, 0.f, 0.f};

  #pragma unroll
  for (int k0 = 0; k0 < 128; k0 += 16) {
    v4s a[2], b[4];
    #pragma unroll
    for (int rt = 0; rt < 2; ++rt) {
      int o = rh * 128 + wv * 32 + rt * 16 + l15;
      a[rt] = __builtin_bit_cast(v4s, *(const uint2*)(A + (size_t)o * 128 + k0 + quad * 4));
    }
    #pragma unroll
    for (int c = 0; c < 4; ++c) {
      int n = nt * 64 + c * 16 + l15;
      b[c] = __builtin_bit_cast(v4s, *(const uint2*)(B + (size_t)n * 128 + k0 + quad * 4));
    }
    #pragma unroll
    for (int rt = 0; rt < 2; ++rt)
      #pragma unroll
      for (int c = 0; c < 4; ++c)
        acc[rt][c] = __builtin_amdgcn_mfma_f32_16x16x16bf16_1k(a[rt], b[c], acc[rt][c], 0, 0, 0);
  }

  const float* Wb = s ? Wb1 : Wb0;
  float* sts = stats + (size_t)s * 512;
  #pragma unroll
  for (int rt = 0; rt < 2; ++rt) {
    float bv[4];
    int ob = rh * 128 + wv * 32 + rt * 16 + quad * 4;
    #pragma unroll
    for (int r = 0; r < 4; ++r) bv[r] = Wb[ob + r];
    #pragma unroll
    for (int r = 0; r < 4; ++r) {
      float sp = 0.f, qp = 0.f;
      #pragma unroll
      for (int c = 0; c < 4; ++c) {
        int n = nt * 64 + c * 16 + l15;
        float v = acc[rt][c][r] + bv[r];
        wy[((size_t)sb * CC + ob + r) * N_SP + n] = v;
        sp += v; qp = fmaf(v, v, qp);
      }
      // reduce over the 16 lanes of this quad (same o)
      #pragma unroll
      for (int off = 1; off < 16; off <<= 1) {
        sp += __shfl_xor(sp, off, 64);
        qp += __shfl_xor(qp, off, 64);
      }
      if (l15 == 0) {
        atomicAdd(&sts[ob + r], sp);
        atomicAdd(&sts[256 + ob + r], qp);
      }
    }
  }
}

// ---------------------------------------------------------------------------
// K4: BN apply (stats precomputed) + residual + ReLU. Single pass.
// grid = 2(sub)*256(o) = 512 x 256.
// ---------------------------------------------------------------------------
__global__ __launch_bounds__(256) void bn_apply(const float* __restrict__ wy,
                                                const float* __restrict__ x0, const float* __restrict__ x1,
                                                const float* __restrict__ g0, const float* __restrict__ b0,
                                                const float* __restrict__ g1, const float* __restrict__ b1,
                                                const float* __restrict__ stats,
                                                float* __restrict__ out)
{
  int o = blockIdx.x % 256;
  int s = blockIdx.x / 256;
  int t = threadIdx.x;
  const float* bng = s ? g1 : g0;
  const float* bnb = s ? b1 : b0;
  const float* xin = s ? x1 : x0;

  float S = stats[s * 512 + o];
  float Q = stats[s * 512 + 256 + o];
  float mean = S * (1.f / 4608.f);
  float var  = Q * (1.f / 4608.f) - mean * mean;
  float rstd = rsqrtf(var + 1e-5f);
  float scale = bng[o] * rstd;
  float shift = bnb[o] - mean * scale;

  #pragma unroll
  for (int b2 = 0; b2 < 2; ++b2) {
    const float* wyp = wy + (size_t)((s*2 + b2)*CC + o) * N_SP;
    const float* xp  = xin + (size_t)(b2*CC + o) * N_SP;
    float* op = out + (size_t)s * BB*CC*N_SP + (size_t)(b2*CC + o) * N_SP;
    #pragma unroll
    for (int n = t; n < N_SP; n += 256) {
      float v = fmaf(wyp[n], scale, shift) + xp[n];
      op[n] = fmaxf(v, 0.f);
    }
  }
}

// ---------------------------------------------------------------------------
extern "C" void kernel_launch(void* const* d_in, const int* in_sizes, int n_in,
                              void* d_out, int out_size, void* d_ws, size_t ws_size,
                              hipStream_t stream)
{
  const float* xc = (const float*)d_in[0];
  const float* xr = (const float*)d_in[1];
  // per-sub input bases: cls=2, reg=12; order: g_w,g_b,theta_w,theta_b,phi_w,phi_b,W_w,W_b,bn_g,bn_b
  PackP pk;
  BiasP bp;
  for (int s = 0; s < 2; ++s) {
    int bs = 2 + s * 10;
    pk.src[s*3 + 0] = (const float*)d_in[bs + 2];  // theta_w
    pk.src[s*3 + 1] = (const float*)d_in[bs + 4];  // phi_w
    pk.src[s*3 + 2] = (const float*)d_in[bs + 0];  // g_w
    pk.src[6 + s]   = (const float*)d_in[bs + 6];  // W_w
    bp.b[s*3 + 0]   = (const float*)d_in[bs + 3];  // theta_b
    bp.b[s*3 + 1]   = (const float*)d_in[bs + 5];  // phi_b
    bp.b[s*3 + 2]   = (const float*)d_in[bs + 1];  // g_b
  }

  char* wsb = (char*)d_ws;
  _Float16*       XT    = (_Float16*)(wsb + OFF_XT);
  _Float16*       WH    = (_Float16*)(wsb + OFF_WH);
  unsigned short* WWB   = (unsigned short*)(wsb + OFF_WWB);
  _Float16*       THETA = (_Float16*)(wsb + OFF_TH);
  _Float16*       PHI   = (_Float16*)(wsb + OFF_PH);
  unsigned short* GT    = (unsigned short*)(wsb + OFF_GT);
  unsigned short* AT    = (unsigned short*)(wsb + OFF_AT);
  float*          WY    = (float*)(wsb + OFF_WY);
  float*          STATS = (float*)(wsb + OFF_STATS);

  prep_kernel<<<1601, 256, 0, stream>>>(pk, WH, WWB, xc, xr, XT, STATS);
  proj_mfma<<<432, 256, 0, stream>>>(bp, WH, XT, THETA, PHI, GT);
  attn_kernel<<<576, 512, 0, stream>>>(THETA, PHI, GT, AT);
  wconv_mfma<<<288, 256, 0, stream>>>(WWB, AT,
                                      (const float*)d_in[9], (const float*)d_in[19], WY, STATS);
  bn_apply<<<512, 256, 0, stream>>>(WY, xc, xr,
                                    (const float*)d_in[10], (const float*)d_in[11],
                                    (const float*)d_in[20], (const float*)d_in[21],
                                    STATS, (float*)d_out);
}